// Round 4
// baseline (2512.298 us; speedup 1.0000x reference)
//
#include <hip/hip_runtime.h>
#include <math.h>

#define NN 100000
#define NE 3200000
#define OUTD 112
#define BROWS 128                 // rows per bucket
#define NBUCK 782                 // ceil(NN / BROWS)
#define FILL_CH 4096              // edges per block in hist/fill
#define FILL_B ((NE + FILL_CH - 1) / FILL_CH)   // 782

// ---------------------------------------------------------------------------
// Kernel 1: ego = entity_embed * (1 + tanh(aux_info @ aux_W.T + aux_b))
// ---------------------------------------------------------------------------
__global__ void fuse_ego_kernel(const float* __restrict__ aux_info,
                                const float* __restrict__ entity,
                                const float* __restrict__ aux_W,
                                const float* __restrict__ aux_b,
                                float* __restrict__ ego0,
                                float* __restrict__ out) {
    int idx = blockIdx.x * blockDim.x + threadIdx.x;
    if (idx >= NN * 64) return;
    int n = idx >> 6;
    int j = idx & 63;
    float a0 = aux_info[n * 3 + 0];
    float a1 = aux_info[n * 3 + 1];
    float a2 = aux_info[n * 3 + 2];
    float w0 = aux_W[j * 3 + 0];
    float w1 = aux_W[j * 3 + 1];
    float w2 = aux_W[j * 3 + 2];
    float t = tanhf(fmaf(a0, w0, fmaf(a1, w1, fmaf(a2, w2, aux_b[j]))));
    float e = entity[idx] * (1.0f + t);
    ego0[idx] = e;
    out[(size_t)n * OUTD + j] = e;
}

// ---------------------------------------------------------------------------
// Bucket build: LDS histogram -> tiny scan -> coalesced-frontier fill.
// Edge record: int2 { col | (row%BROWS)<<17 , val-as-bits }.
// ---------------------------------------------------------------------------
__global__ void bhist_kernel(const int* __restrict__ rows, int* __restrict__ gcount) {
    __shared__ int h[NBUCK];
    for (int i = threadIdx.x; i < NBUCK; i += 256) h[i] = 0;
    __syncthreads();
    int base = blockIdx.x * FILL_CH;
    int nE = NE - base; if (nE > FILL_CH) nE = FILL_CH;
    for (int i = threadIdx.x; i < nE; i += 256)
        atomicAdd(&h[rows[base + i] >> 7], 1);
    __syncthreads();
    for (int i = threadIdx.x; i < NBUCK; i += 256)
        if (h[i]) atomicAdd(&gcount[i], h[i]);
}

// one block of 1024 threads scans NBUCK counts -> bucket_base (excl), gcursor
__global__ void bscan_kernel(const int* __restrict__ gcount,
                             int* __restrict__ bucket_base,
                             int* __restrict__ gcursor) {
    __shared__ int sh[1024];
    int t = threadIdx.x;
    int v = (t < NBUCK) ? gcount[t] : 0;
    sh[t] = v;
    __syncthreads();
    for (int off = 1; off < 1024; off <<= 1) {
        int u = (t >= off) ? sh[t - off] : 0;
        __syncthreads();
        sh[t] += u;
        __syncthreads();
    }
    if (t < NBUCK) {
        int excl = sh[t] - v;
        bucket_base[t] = excl;
        gcursor[t] = excl;
    }
    if (t == 1023) bucket_base[NBUCK] = sh[1023];
}

__global__ void bucket_fill_kernel(const int* __restrict__ rows,
                                   const int* __restrict__ cols,
                                   const float* __restrict__ vals,
                                   int* __restrict__ gcursor,
                                   int2* __restrict__ edges_b) {
    __shared__ int rowsL[FILL_CH];        // 16 KB
    __shared__ int hcnt[NBUCK];
    __shared__ int curs[NBUCK];
    int base = blockIdx.x * FILL_CH;
    int nE = NE - base; if (nE > FILL_CH) nE = FILL_CH;
    for (int i = threadIdx.x; i < NBUCK; i += 256) hcnt[i] = 0;
    __syncthreads();
    for (int i = threadIdx.x; i < nE; i += 256) {
        int r = rows[base + i];
        rowsL[i] = r;
        atomicAdd(&hcnt[r >> 7], 1);
    }
    __syncthreads();
    for (int b = threadIdx.x; b < NBUCK; b += 256) {
        int c = hcnt[b];
        curs[b] = c ? atomicAdd(&gcursor[b], c) : 0;
    }
    __syncthreads();
    for (int i = threadIdx.x; i < nE; i += 256) {
        int r = rowsL[i];
        int b = r >> 7;
        int p = atomicAdd(&curs[b], 1);
        edges_b[p] = make_int2(cols[base + i] | ((r & (BROWS - 1)) << 17),
                               __float_as_int(vals[base + i]));
    }
}

// ---------------------------------------------------------------------------
// Bucket gather: one block per bucket; side tile [BROWS][D] accumulated in
// LDS via ds_add. Wave loads 64 edge descriptors coalesced, broadcasts each
// via shfl; lane j owns feature j (D=64) / features split over half-waves
// (D=32, two edges in flight per wave).
// ---------------------------------------------------------------------------
__global__ void bucket_gather64(const float* __restrict__ ego,
                                const int2* __restrict__ edges_b,
                                const int* __restrict__ bucket_base,
                                float* __restrict__ side) {
    __shared__ float tile[BROWS * 64];    // 32 KB
    for (int i = threadIdx.x; i < BROWS * 64; i += 256) tile[i] = 0.0f;
    __syncthreads();
    int b = blockIdx.x;
    int beg = bucket_base[b], end = bucket_base[b + 1];
    int wave = threadIdx.x >> 6, lane = threadIdx.x & 63;
    for (int i0 = beg + wave * 64; i0 < end; i0 += 4 * 64) {
        int2 ed = (i0 + lane < end) ? edges_b[i0 + lane] : make_int2(0, 0);
        int cnt = end - i0; if (cnt > 64) cnt = 64;
        if (cnt == 64) {
#pragma unroll 4
            for (int k = 0; k < 64; ++k) {
                int u = __shfl(ed.x, k, 64);
                float v = __int_as_float(__shfl(ed.y, k, 64));
                int col = u & 0x1FFFF;
                int rl = (u >> 17) & (BROWS - 1);
                float g = ego[(size_t)col * 64 + lane];
                atomicAdd(&tile[rl * 64 + lane], v * g);
            }
        } else {
            for (int k = 0; k < cnt; ++k) {
                int u = __shfl(ed.x, k, 64);
                float v = __int_as_float(__shfl(ed.y, k, 64));
                int col = u & 0x1FFFF;
                int rl = (u >> 17) & (BROWS - 1);
                float g = ego[(size_t)col * 64 + lane];
                atomicAdd(&tile[rl * 64 + lane], v * g);
            }
        }
    }
    __syncthreads();
    int n0 = b * BROWS;
    for (int i = threadIdx.x; i < BROWS * 64; i += 256) {
        int n = n0 + (i >> 6);
        if (n < NN) side[(size_t)n * 64 + (i & 63)] = tile[i];
    }
}

__global__ void bucket_gather32(const float* __restrict__ ego,
                                const int2* __restrict__ edges_b,
                                const int* __restrict__ bucket_base,
                                float* __restrict__ side) {
    __shared__ float tile[BROWS * 32];    // 16 KB
    for (int i = threadIdx.x; i < BROWS * 32; i += 256) tile[i] = 0.0f;
    __syncthreads();
    int b = blockIdx.x;
    int beg = bucket_base[b], end = bucket_base[b + 1];
    int wave = threadIdx.x >> 6, lane = threadIdx.x & 63;
    int half = lane >> 5;        // which edge of the pair this lane serves
    int l32 = lane & 31;         // feature index
    for (int i0 = beg + wave * 64; i0 < end; i0 += 4 * 64) {
        int2 ed = (i0 + lane < end) ? edges_b[i0 + lane] : make_int2(0, 0);
        int cnt = end - i0; if (cnt > 64) cnt = 64;
        for (int k2 = 0; k2 < cnt; k2 += 2) {
            int idx = k2 + half;
            int u = __shfl(ed.x, idx, 64);
            float v = __int_as_float(__shfl(ed.y, idx, 64));
            if (idx < cnt) {
                int col = u & 0x1FFFF;
                int rl = (u >> 17) & (BROWS - 1);
                float g = ego[(size_t)col * 32 + l32];
                atomicAdd(&tile[rl * 32 + l32], v * g);
            }
        }
    }
    __syncthreads();
    int n0 = b * BROWS;
    for (int i = threadIdx.x; i < BROWS * 32; i += 256) {
        int n = n0 + (i >> 5);
        if (n < NN) side[(size_t)n * 32 + (i & 31)] = tile[i];
    }
}

// ---------------------------------------------------------------------------
// Bi-interaction layer + l2norm epilogue.
// ---------------------------------------------------------------------------
template <int DIN, int DOUT, int NB>
__global__ void layer_kernel(const float* __restrict__ ego,
                             const float* __restrict__ side,
                             const float* __restrict__ W1,
                             const float* __restrict__ b1,
                             const float* __restrict__ W2,
                             const float* __restrict__ b2,
                             float* __restrict__ ego_next,   // may be nullptr
                             float* __restrict__ out,
                             int out_off) {
    __shared__ float W1t[DIN][DOUT + 1];
    __shared__ float W2t[DIN][DOUT + 1];
    __shared__ float egoL[NB][DIN];
    __shared__ float sideL[NB][DIN];

    for (int i = threadIdx.x; i < DIN * DOUT; i += blockDim.x) {
        int j = i / DIN;
        int k = i - j * DIN;
        W1t[k][j] = W1[i];
        W2t[k][j] = W2[i];
    }
    int node0 = blockIdx.x * NB;
    for (int i = threadIdx.x; i < NB * DIN; i += blockDim.x) {
        int m = i / DIN;
        int k = i - m * DIN;
        int n = node0 + m;
        if (n < NN) {
            egoL[m][k] = ego[(size_t)n * DIN + k];
            sideL[m][k] = side[(size_t)n * DIN + k];
        }
    }
    __syncthreads();

    int m = threadIdx.x / DOUT;
    int j = threadIdx.x % DOUT;
    int n = node0 + m;
    if (n >= NN) return;

    float s = b1[j];
    float bb = b2[j];
#pragma unroll
    for (int k = 0; k < DIN; ++k) {
        float eg = egoL[m][k];
        float sd = sideL[m][k];
        s = fmaf(eg + sd, W1t[k][j], s);
        bb = fmaf(eg * sd, W2t[k][j], bb);
    }
    s = (s > 0.0f) ? s : 0.01f * s;
    bb = (bb > 0.0f) ? bb : 0.01f * bb;
    float v = s + bb;
    if (ego_next) ego_next[(size_t)n * DOUT + j] = v;

    float sq = v * v;
#pragma unroll
    for (int off = DOUT / 2; off > 0; off >>= 1)
        sq += __shfl_xor(sq, off, DOUT);
    float norm = sqrtf(sq);
    norm = (norm > 1e-12f) ? norm : 1e-12f;
    out[(size_t)n * OUTD + out_off + j] = v / norm;
}

// ---------------------------------------------------------------------------
extern "C" void kernel_launch(void* const* d_in, const int* in_sizes, int n_in,
                              void* d_out, int out_size, void* d_ws, size_t ws_size,
                              hipStream_t stream) {
    const float* aux_info  = (const float*)d_in[0];
    const float* entity    = (const float*)d_in[1];
    const float* aux_W     = (const float*)d_in[2];
    const float* aux_b     = (const float*)d_in[3];
    const float* edge_vals = (const float*)d_in[4];
    const int*   edge_rows = (const int*)d_in[5];
    const int*   edge_cols = (const int*)d_in[6];
    const float* W1_0 = (const float*)d_in[7];
    const float* b1_0 = (const float*)d_in[8];
    const float* W2_0 = (const float*)d_in[9];
    const float* b2_0 = (const float*)d_in[10];
    const float* W1_1 = (const float*)d_in[11];
    const float* b1_1 = (const float*)d_in[12];
    const float* W2_1 = (const float*)d_in[13];
    const float* b2_1 = (const float*)d_in[14];
    float* out = (float*)d_out;

    // workspace layout (4-byte elements):
    // ego0[N*64] side0[N*64] ego1[N*32] side1[N*32] edges_b[2*E]
    // bucket_base[NBUCK+1] gcount[NBUCK]
    float* ego0  = (float*)d_ws;
    float* side0 = ego0 + (size_t)NN * 64;
    float* ego1  = side0 + (size_t)NN * 64;
    float* side1 = ego1 + (size_t)NN * 32;
    int2*  edges_b = (int2*)(side1 + (size_t)NN * 32);
    int* bucket_base = (int*)(edges_b + NE);
    int* gcount = bucket_base + NBUCK + 1;   // doubles as gcursor after scan

    // --- bucket build (graph shared by both layers) ---
    hipMemsetAsync(gcount, 0, (size_t)NBUCK * sizeof(int), stream);
    bhist_kernel<<<FILL_B, 256, 0, stream>>>(edge_rows, gcount);
    bscan_kernel<<<1, 1024, 0, stream>>>(gcount, bucket_base, gcount);
    bucket_fill_kernel<<<FILL_B, 256, 0, stream>>>(
        edge_rows, edge_cols, edge_vals, gcount, edges_b);

    // --- 1) holographic fusion -> ego0, out[:,0:64] ---
    {
        int total = NN * 64;
        fuse_ego_kernel<<<(total + 255) / 256, 256, 0, stream>>>(
            aux_info, entity, aux_W, aux_b, ego0, out);
    }
    // --- 2) layer 0 segment-sum (bucket accumulate) ---
    bucket_gather64<<<NBUCK, 256, 0, stream>>>(ego0, edges_b, bucket_base, side0);
    // --- 3) layer 0 transform -> ego1, out[:,64:96] ---
    layer_kernel<64, 32, 8><<<(NN + 7) / 8, 256, 0, stream>>>(
        ego0, side0, W1_0, b1_0, W2_0, b2_0, ego1, out, 64);
    // --- 4) layer 1 segment-sum ---
    bucket_gather32<<<NBUCK, 256, 0, stream>>>(ego1, edges_b, bucket_base, side1);
    // --- 5) layer 1 transform -> out[:,96:112] ---
    layer_kernel<32, 16, 16><<<(NN + 15) / 16, 256, 0, stream>>>(
        ego1, side1, W1_1, b1_1, W2_1, b2_1, nullptr, out, 96);
}

// Round 5
// 534.684 us; speedup vs baseline: 4.6987x; 4.6987x over previous
//
#include <hip/hip_runtime.h>
#include <math.h>

#define NN 100000
#define NE 3200000
#define OUTD 112
#define BROWS 128                 // rows per bucket
#define NBUCK 782                 // ceil(NN / BROWS)
#define FILL_CH 4096              // edges per block in hist/fill
#define FILL_B ((NE + FILL_CH - 1) / FILL_CH)   // 782

// ---------------------------------------------------------------------------
// Kernel 1: ego = entity_embed * (1 + tanh(aux_info @ aux_W.T + aux_b))
// ---------------------------------------------------------------------------
__global__ void fuse_ego_kernel(const float* __restrict__ aux_info,
                                const float* __restrict__ entity,
                                const float* __restrict__ aux_W,
                                const float* __restrict__ aux_b,
                                float* __restrict__ ego0,
                                float* __restrict__ out) {
    int idx = blockIdx.x * blockDim.x + threadIdx.x;
    if (idx >= NN * 64) return;
    int n = idx >> 6;
    int j = idx & 63;
    float a0 = aux_info[n * 3 + 0];
    float a1 = aux_info[n * 3 + 1];
    float a2 = aux_info[n * 3 + 2];
    float w0 = aux_W[j * 3 + 0];
    float w1 = aux_W[j * 3 + 1];
    float w2 = aux_W[j * 3 + 2];
    float t = tanhf(fmaf(a0, w0, fmaf(a1, w1, fmaf(a2, w2, aux_b[j]))));
    float e = entity[idx] * (1.0f + t);
    ego0[idx] = e;
    out[(size_t)n * OUTD + j] = e;
}

// ---------------------------------------------------------------------------
// CSR build, stage 1: bucket (128-row granularity) counting sort.
// Edge record in edges_b: int2 { col | (row%BROWS)<<17 , val-as-bits }.
// ---------------------------------------------------------------------------
__global__ void bhist_kernel(const int* __restrict__ rows, int* __restrict__ gcount) {
    __shared__ int h[NBUCK];
    for (int i = threadIdx.x; i < NBUCK; i += 256) h[i] = 0;
    __syncthreads();
    int base = blockIdx.x * FILL_CH;
    int nE = NE - base; if (nE > FILL_CH) nE = FILL_CH;
    for (int i = threadIdx.x; i < nE; i += 256)
        atomicAdd(&h[rows[base + i] >> 7], 1);
    __syncthreads();
    for (int i = threadIdx.x; i < NBUCK; i += 256)
        if (h[i]) atomicAdd(&gcount[i], h[i]);
}

// one block of 1024 threads scans NBUCK counts -> bucket_base (excl) + cursor
__global__ void bscan_kernel(const int* __restrict__ gcount,
                             int* __restrict__ bucket_base,
                             int* __restrict__ gcursor) {
    __shared__ int sh[1024];
    int t = threadIdx.x;
    int v = (t < NBUCK) ? gcount[t] : 0;
    sh[t] = v;
    __syncthreads();
    for (int off = 1; off < 1024; off <<= 1) {
        int u = (t >= off) ? sh[t - off] : 0;
        __syncthreads();
        sh[t] += u;
        __syncthreads();
    }
    if (t < NBUCK) {
        int excl = sh[t] - v;
        bucket_base[t] = excl;
        gcursor[t] = excl;
    }
    if (t == 1023) bucket_base[NBUCK] = sh[1023];
}

__global__ void bucket_fill_kernel(const int* __restrict__ rows,
                                   const int* __restrict__ cols,
                                   const float* __restrict__ vals,
                                   int* __restrict__ gcursor,
                                   int2* __restrict__ edges_b) {
    __shared__ int rowsL[FILL_CH];        // 16 KB
    __shared__ int hcnt[NBUCK];
    __shared__ int curs[NBUCK];
    int base = blockIdx.x * FILL_CH;
    int nE = NE - base; if (nE > FILL_CH) nE = FILL_CH;
    for (int i = threadIdx.x; i < NBUCK; i += 256) hcnt[i] = 0;
    __syncthreads();
    for (int i = threadIdx.x; i < nE; i += 256) {
        int r = rows[base + i];
        rowsL[i] = r;
        atomicAdd(&hcnt[r >> 7], 1);
    }
    __syncthreads();
    for (int b = threadIdx.x; b < NBUCK; b += 256) {
        int c = hcnt[b];
        curs[b] = c ? atomicAdd(&gcursor[b], c) : 0;
    }
    __syncthreads();
    for (int i = threadIdx.x; i < nE; i += 256) {
        int r = rowsL[i];
        int b = r >> 7;
        int p = atomicAdd(&curs[b], 1);
        edges_b[p] = make_int2(cols[base + i] | ((r & (BROWS - 1)) << 17),
                               __float_as_int(vals[base + i]));
    }
}

// ---------------------------------------------------------------------------
// CSR build, stage 2: within-bucket counting sort -> row-sorted edges +
// row_ptr. One block per bucket; all writes land in the bucket's contiguous
// window. Bucket edges are read twice (second pass L2-hot).
// ---------------------------------------------------------------------------
__global__ void csr_sort_kernel(const int2* __restrict__ edges_b,
                                const int* __restrict__ bucket_base,
                                int2* __restrict__ edges,
                                int* __restrict__ row_ptr) {
    __shared__ int cnt[BROWS];
    __shared__ int scn[BROWS];
    __shared__ int curs[BROWS];
    int b = blockIdx.x;
    int beg = bucket_base[b], end = bucket_base[b + 1];
    if (threadIdx.x < BROWS) cnt[threadIdx.x] = 0;
    __syncthreads();
    for (int i = beg + threadIdx.x; i < end; i += 256)
        atomicAdd(&cnt[(edges_b[i].x >> 17) & (BROWS - 1)], 1);
    __syncthreads();
    if (threadIdx.x < BROWS) scn[threadIdx.x] = cnt[threadIdx.x];
    __syncthreads();
    for (int off = 1; off < BROWS; off <<= 1) {
        int v = 0;
        if (threadIdx.x < BROWS && threadIdx.x >= off) v = scn[threadIdx.x - off];
        __syncthreads();
        if (threadIdx.x < BROWS && threadIdx.x >= off) scn[threadIdx.x] += v;
        __syncthreads();
    }
    if (threadIdx.x < BROWS) {
        int excl = scn[threadIdx.x] - cnt[threadIdx.x];
        int n = b * BROWS + threadIdx.x;
        if (n <= NN) row_ptr[n] = beg + excl;   // n==NN lands here (last bucket)
        curs[threadIdx.x] = beg + excl;
    }
    __syncthreads();
    for (int i = beg + threadIdx.x; i < end; i += 256) {
        int2 e = edges_b[i];
        int rl = (e.x >> 17) & (BROWS - 1);
        int p = atomicAdd(&curs[rl], 1);
        edges[p] = make_int2(e.x & 0x1FFFF, e.y);
    }
}

// ---------------------------------------------------------------------------
// Pull-based segment sum (R3 design): D lanes per node, lane j owns feature
// j; unroll 8 keeps 8 independent gather loads in flight per lane.
// ---------------------------------------------------------------------------
template <int D>
__global__ void gather_kernel(const float* __restrict__ ego,
                              const int2* __restrict__ edges,
                              const int* __restrict__ row_ptr,
                              float* __restrict__ side) {
    int g = threadIdx.x / D;
    int n = blockIdx.x * (256 / D) + g;
    int j = threadIdx.x % D;
    if (n >= NN) return;
    int beg = row_ptr[n];
    int end = row_ptr[n + 1];
    float acc = 0.0f;
    int i = beg;
    for (; i + 8 <= end; i += 8) {
        int2 e[8];
        float gv[8];
#pragma unroll
        for (int k = 0; k < 8; ++k) e[k] = edges[i + k];
#pragma unroll
        for (int k = 0; k < 8; ++k) gv[k] = ego[(size_t)e[k].x * D + j];
#pragma unroll
        for (int k = 0; k < 8; ++k) acc = fmaf(__int_as_float(e[k].y), gv[k], acc);
    }
    for (; i < end; ++i) {
        int2 e = edges[i];
        acc = fmaf(__int_as_float(e.y), ego[(size_t)e.x * D + j], acc);
    }
    side[(size_t)n * D + j] = acc;
}

// ---------------------------------------------------------------------------
// Bi-interaction layer + l2norm epilogue.
// ---------------------------------------------------------------------------
template <int DIN, int DOUT, int NB>
__global__ void layer_kernel(const float* __restrict__ ego,
                             const float* __restrict__ side,
                             const float* __restrict__ W1,
                             const float* __restrict__ b1,
                             const float* __restrict__ W2,
                             const float* __restrict__ b2,
                             float* __restrict__ ego_next,   // may be nullptr
                             float* __restrict__ out,
                             int out_off) {
    __shared__ float W1t[DIN][DOUT + 1];
    __shared__ float W2t[DIN][DOUT + 1];
    __shared__ float egoL[NB][DIN];
    __shared__ float sideL[NB][DIN];

    for (int i = threadIdx.x; i < DIN * DOUT; i += blockDim.x) {
        int j = i / DIN;
        int k = i - j * DIN;
        W1t[k][j] = W1[i];
        W2t[k][j] = W2[i];
    }
    int node0 = blockIdx.x * NB;
    for (int i = threadIdx.x; i < NB * DIN; i += blockDim.x) {
        int m = i / DIN;
        int k = i - m * DIN;
        int n = node0 + m;
        if (n < NN) {
            egoL[m][k] = ego[(size_t)n * DIN + k];
            sideL[m][k] = side[(size_t)n * DIN + k];
        }
    }
    __syncthreads();

    int m = threadIdx.x / DOUT;
    int j = threadIdx.x % DOUT;
    int n = node0 + m;
    if (n >= NN) return;

    float s = b1[j];
    float bb = b2[j];
#pragma unroll
    for (int k = 0; k < DIN; ++k) {
        float eg = egoL[m][k];
        float sd = sideL[m][k];
        s = fmaf(eg + sd, W1t[k][j], s);
        bb = fmaf(eg * sd, W2t[k][j], bb);
    }
    s = (s > 0.0f) ? s : 0.01f * s;
    bb = (bb > 0.0f) ? bb : 0.01f * bb;
    float v = s + bb;
    if (ego_next) ego_next[(size_t)n * DOUT + j] = v;

    float sq = v * v;
#pragma unroll
    for (int off = DOUT / 2; off > 0; off >>= 1)
        sq += __shfl_xor(sq, off, DOUT);
    float norm = sqrtf(sq);
    norm = (norm > 1e-12f) ? norm : 1e-12f;
    out[(size_t)n * OUTD + out_off + j] = v / norm;
}

// ---------------------------------------------------------------------------
extern "C" void kernel_launch(void* const* d_in, const int* in_sizes, int n_in,
                              void* d_out, int out_size, void* d_ws, size_t ws_size,
                              hipStream_t stream) {
    const float* aux_info  = (const float*)d_in[0];
    const float* entity    = (const float*)d_in[1];
    const float* aux_W     = (const float*)d_in[2];
    const float* aux_b     = (const float*)d_in[3];
    const float* edge_vals = (const float*)d_in[4];
    const int*   edge_rows = (const int*)d_in[5];
    const int*   edge_cols = (const int*)d_in[6];
    const float* W1_0 = (const float*)d_in[7];
    const float* b1_0 = (const float*)d_in[8];
    const float* W2_0 = (const float*)d_in[9];
    const float* b2_0 = (const float*)d_in[10];
    const float* W1_1 = (const float*)d_in[11];
    const float* b1_1 = (const float*)d_in[12];
    const float* W2_1 = (const float*)d_in[13];
    const float* b2_1 = (const float*)d_in[14];
    float* out = (float*)d_out;

    // workspace layout (4-byte elements). side0 ALIASES edges_b: edges_b is
    // dead after csr_sort, side0 is first written by gather64 (later).
    //   [ edges_b | side0 ][ ego0 ][ edges ][ ego1 ][ side1 ][ row_ptr ... ]
    float* region0 = (float*)d_ws;                    // NE*2 == NN*64 * (6.4M/6.4M)
    int2*  edges_b = (int2*)region0;                  // 3.2M int2 = 6.4M words
    float* side0   = region0;                         // 6.4M words (alias)
    float* ego0    = region0 + (size_t)NE * 2;        // 6.4M words
    int2*  edges   = (int2*)(ego0 + (size_t)NN * 64); // 6.4M words
    float* ego1    = (float*)(edges + NE);            // 3.2M words
    float* side1   = ego1 + (size_t)NN * 32;          // 3.2M words
    int* row_ptr     = (int*)(side1 + (size_t)NN * 32);
    int* bucket_base = row_ptr + NN + 1;
    int* gcount      = bucket_base + NBUCK + 1;       // reused as bucket cursor

    // --- CSR build (graph shared by both layers) ---
    hipMemsetAsync(gcount, 0, (size_t)NBUCK * sizeof(int), stream);
    bhist_kernel<<<FILL_B, 256, 0, stream>>>(edge_rows, gcount);
    bscan_kernel<<<1, 1024, 0, stream>>>(gcount, bucket_base, gcount);
    bucket_fill_kernel<<<FILL_B, 256, 0, stream>>>(
        edge_rows, edge_cols, edge_vals, gcount, edges_b);
    csr_sort_kernel<<<NBUCK, 256, 0, stream>>>(edges_b, bucket_base, edges, row_ptr);

    // --- 1) holographic fusion -> ego0, out[:,0:64] ---
    {
        int total = NN * 64;
        fuse_ego_kernel<<<(total + 255) / 256, 256, 0, stream>>>(
            aux_info, entity, aux_W, aux_b, ego0, out);
    }
    // --- 2) layer 0 segment-sum (pull) ---
    gather_kernel<64><<<(NN + 3) / 4, 256, 0, stream>>>(ego0, edges, row_ptr, side0);
    // --- 3) layer 0 transform -> ego1, out[:,64:96] ---
    layer_kernel<64, 32, 8><<<(NN + 7) / 8, 256, 0, stream>>>(
        ego0, side0, W1_0, b1_0, W2_0, b2_0, ego1, out, 64);
    // --- 4) layer 1 segment-sum (pull) ---
    gather_kernel<32><<<(NN + 7) / 8, 256, 0, stream>>>(ego1, edges, row_ptr, side1);
    // --- 5) layer 1 transform -> out[:,96:112] ---
    layer_kernel<32, 16, 16><<<(NN + 15) / 16, 256, 0, stream>>>(
        ego1, side1, W1_1, b1_1, W2_1, b2_1, nullptr, out, 96);
}

// Round 6
// 455.959 us; speedup vs baseline: 5.5099x; 1.1727x over previous
//
#include <hip/hip_runtime.h>
#include <math.h>

#define NN 100000
#define NE 3200000
#define OUTD 112
#define BROWS 128                 // rows per bucket
#define NBUCK 782                 // ceil(NN / BROWS)
#define FILL_CH 4096              // edges per block in hist/fill
#define FILL_B ((NE + FILL_CH - 1) / FILL_CH)   // 782

// round-to-nearest-even fp32 -> bf16 (as raw 16 bits)
__device__ inline unsigned short f32_to_bf16(float f) {
    unsigned u = __float_as_uint(f);
    u += 0x7FFFu + ((u >> 16) & 1u);
    return (unsigned short)(u >> 16);
}
__device__ inline float bf16_bits_to_f32(unsigned b) {
    return __uint_as_float(b << 16);
}

// ---------------------------------------------------------------------------
// Kernel 1: ego = entity_embed * (1 + tanh(aux_info @ aux_W.T + aux_b))
// writes fp32 ego0 (layer input), bf16 ego0h (gather input), out[:,0:64].
// ---------------------------------------------------------------------------
__global__ void fuse_ego_kernel(const float* __restrict__ aux_info,
                                const float* __restrict__ entity,
                                const float* __restrict__ aux_W,
                                const float* __restrict__ aux_b,
                                float* __restrict__ ego0,
                                unsigned short* __restrict__ ego0h,
                                float* __restrict__ out) {
    int idx = blockIdx.x * blockDim.x + threadIdx.x;
    if (idx >= NN * 64) return;
    int n = idx >> 6;
    int j = idx & 63;
    float a0 = aux_info[n * 3 + 0];
    float a1 = aux_info[n * 3 + 1];
    float a2 = aux_info[n * 3 + 2];
    float w0 = aux_W[j * 3 + 0];
    float w1 = aux_W[j * 3 + 1];
    float w2 = aux_W[j * 3 + 2];
    float t = tanhf(fmaf(a0, w0, fmaf(a1, w1, fmaf(a2, w2, aux_b[j]))));
    float e = entity[idx] * (1.0f + t);
    ego0[idx] = e;
    ego0h[idx] = f32_to_bf16(e);
    out[(size_t)n * OUTD + j] = e;
}

// ---------------------------------------------------------------------------
// CSR build, stage 1: bucket (128-row granularity) counting sort.
// Stage-1 record: int2 { col | (row%BROWS)<<17 , val-as-fp32-bits }.
// ---------------------------------------------------------------------------
__global__ void bhist_kernel(const int* __restrict__ rows, int* __restrict__ gcount) {
    __shared__ int h[NBUCK];
    for (int i = threadIdx.x; i < NBUCK; i += 256) h[i] = 0;
    __syncthreads();
    int base = blockIdx.x * FILL_CH;
    int nE = NE - base; if (nE > FILL_CH) nE = FILL_CH;
    for (int i = threadIdx.x; i < nE; i += 256)
        atomicAdd(&h[rows[base + i] >> 7], 1);
    __syncthreads();
    for (int i = threadIdx.x; i < NBUCK; i += 256)
        if (h[i]) atomicAdd(&gcount[i], h[i]);
}

__global__ void bscan_kernel(const int* __restrict__ gcount,
                             int* __restrict__ bucket_base,
                             int* __restrict__ gcursor) {
    __shared__ int sh[1024];
    int t = threadIdx.x;
    int v = (t < NBUCK) ? gcount[t] : 0;
    sh[t] = v;
    __syncthreads();
    for (int off = 1; off < 1024; off <<= 1) {
        int u = (t >= off) ? sh[t - off] : 0;
        __syncthreads();
        sh[t] += u;
        __syncthreads();
    }
    if (t < NBUCK) {
        int excl = sh[t] - v;
        bucket_base[t] = excl;
        gcursor[t] = excl;
    }
    if (t == 1023) bucket_base[NBUCK] = sh[1023];
}

__global__ void bucket_fill_kernel(const int* __restrict__ rows,
                                   const int* __restrict__ cols,
                                   const float* __restrict__ vals,
                                   int* __restrict__ gcursor,
                                   int2* __restrict__ edges_b) {
    __shared__ int rowsL[FILL_CH];        // 16 KB
    __shared__ int hcnt[NBUCK];
    __shared__ int curs[NBUCK];
    int base = blockIdx.x * FILL_CH;
    int nE = NE - base; if (nE > FILL_CH) nE = FILL_CH;
    for (int i = threadIdx.x; i < NBUCK; i += 256) hcnt[i] = 0;
    __syncthreads();
    for (int i = threadIdx.x; i < nE; i += 256) {
        int r = rows[base + i];
        rowsL[i] = r;
        atomicAdd(&hcnt[r >> 7], 1);
    }
    __syncthreads();
    for (int b = threadIdx.x; b < NBUCK; b += 256) {
        int c = hcnt[b];
        curs[b] = c ? atomicAdd(&gcursor[b], c) : 0;
    }
    __syncthreads();
    for (int i = threadIdx.x; i < nE; i += 256) {
        int r = rowsL[i];
        int b = r >> 7;
        int p = atomicAdd(&curs[b], 1);
        edges_b[p] = make_int2(cols[base + i] | ((r & (BROWS - 1)) << 17),
                               __float_as_int(vals[base + i]));
    }
}

// ---------------------------------------------------------------------------
// CSR build, stage 2: within-bucket counting sort -> row-sorted PACKED edges
// (uint32 = col | bf15(val)<<17) + row_ptr. One block per bucket.
// ---------------------------------------------------------------------------
__global__ void csr_sort_kernel(const int2* __restrict__ edges_b,
                                const int* __restrict__ bucket_base,
                                unsigned int* __restrict__ edges,
                                int* __restrict__ row_ptr) {
    __shared__ int cnt[BROWS];
    __shared__ int scn[BROWS];
    __shared__ int curs[BROWS];
    int b = blockIdx.x;
    int beg = bucket_base[b], end = bucket_base[b + 1];
    if (threadIdx.x < BROWS) cnt[threadIdx.x] = 0;
    __syncthreads();
    for (int i = beg + threadIdx.x; i < end; i += 256)
        atomicAdd(&cnt[(edges_b[i].x >> 17) & (BROWS - 1)], 1);
    __syncthreads();
    if (threadIdx.x < BROWS) scn[threadIdx.x] = cnt[threadIdx.x];
    __syncthreads();
    for (int off = 1; off < BROWS; off <<= 1) {
        int v = 0;
        if (threadIdx.x < BROWS && threadIdx.x >= off) v = scn[threadIdx.x - off];
        __syncthreads();
        if (threadIdx.x < BROWS && threadIdx.x >= off) scn[threadIdx.x] += v;
        __syncthreads();
    }
    if (threadIdx.x < BROWS) {
        int excl = scn[threadIdx.x] - cnt[threadIdx.x];
        int n = b * BROWS + threadIdx.x;
        if (n <= NN) row_ptr[n] = beg + excl;   // n==NN covered by last bucket
        curs[threadIdx.x] = beg + excl;
    }
    __syncthreads();
    for (int i = beg + threadIdx.x; i < end; i += 256) {
        int2 e = edges_b[i];
        int rl = (e.x >> 17) & (BROWS - 1);
        int p = atomicAdd(&curs[rl], 1);
        unsigned int vb = f32_to_bf16(__int_as_float(e.y)) & 0x7FFFu;  // val>=0
        edges[p] = (unsigned int)(e.x & 0x1FFFF) | (vb << 17);
    }
}

// ---------------------------------------------------------------------------
// Pull-based segment sum, bf16 inputs, fp32 accumulate.
// L = D/2 lanes per node; each lane owns a feature PAIR (ushort2 load).
// Unroll 8 keeps 8 independent gather loads in flight per lane.
// ---------------------------------------------------------------------------
template <int D>
__global__ void gather_kernel(const ushort2* __restrict__ egoh,
                              const unsigned int* __restrict__ edges,
                              const int* __restrict__ row_ptr,
                              float* __restrict__ side) {
    constexpr int L = D / 2;
    int n = blockIdx.x * (256 / L) + threadIdx.x / L;
    int j = threadIdx.x % L;
    if (n >= NN) return;
    int beg = row_ptr[n];
    int end = row_ptr[n + 1];
    float a0 = 0.0f, a1 = 0.0f;
    int i = beg;
    for (; i + 8 <= end; i += 8) {
        unsigned int e[8];
        ushort2 gv[8];
#pragma unroll
        for (int k = 0; k < 8; ++k) e[k] = edges[i + k];
#pragma unroll
        for (int k = 0; k < 8; ++k) gv[k] = egoh[(size_t)(e[k] & 0x1FFFFu) * L + j];
#pragma unroll
        for (int k = 0; k < 8; ++k) {
            float v = bf16_bits_to_f32(e[k] >> 17);   // sign=0
            a0 = fmaf(v, bf16_bits_to_f32(gv[k].x), a0);
            a1 = fmaf(v, bf16_bits_to_f32(gv[k].y), a1);
        }
    }
    for (; i < end; ++i) {
        unsigned int e = edges[i];
        ushort2 g = egoh[(size_t)(e & 0x1FFFFu) * L + j];
        float v = bf16_bits_to_f32(e >> 17);
        a0 = fmaf(v, bf16_bits_to_f32(g.x), a0);
        a1 = fmaf(v, bf16_bits_to_f32(g.y), a1);
    }
    side[(size_t)n * D + 2 * j]     = a0;
    side[(size_t)n * D + 2 * j + 1] = a1;
}

// ---------------------------------------------------------------------------
// Bi-interaction layer + l2norm epilogue. Optionally emits bf16 copy of
// ego_next for the next gather.
// ---------------------------------------------------------------------------
template <int DIN, int DOUT, int NB>
__global__ void layer_kernel(const float* __restrict__ ego,
                             const float* __restrict__ side,
                             const float* __restrict__ W1,
                             const float* __restrict__ b1,
                             const float* __restrict__ W2,
                             const float* __restrict__ b2,
                             float* __restrict__ ego_next,          // nullable
                             unsigned short* __restrict__ ego_next_h, // nullable
                             float* __restrict__ out,
                             int out_off) {
    __shared__ float W1t[DIN][DOUT + 1];
    __shared__ float W2t[DIN][DOUT + 1];
    __shared__ float egoL[NB][DIN];
    __shared__ float sideL[NB][DIN];

    for (int i = threadIdx.x; i < DIN * DOUT; i += blockDim.x) {
        int j = i / DIN;
        int k = i - j * DIN;
        W1t[k][j] = W1[i];
        W2t[k][j] = W2[i];
    }
    int node0 = blockIdx.x * NB;
    for (int i = threadIdx.x; i < NB * DIN; i += blockDim.x) {
        int m = i / DIN;
        int k = i - m * DIN;
        int n = node0 + m;
        if (n < NN) {
            egoL[m][k] = ego[(size_t)n * DIN + k];
            sideL[m][k] = side[(size_t)n * DIN + k];
        }
    }
    __syncthreads();

    int m = threadIdx.x / DOUT;
    int j = threadIdx.x % DOUT;
    int n = node0 + m;
    if (n >= NN) return;

    float s = b1[j];
    float bb = b2[j];
#pragma unroll
    for (int k = 0; k < DIN; ++k) {
        float eg = egoL[m][k];
        float sd = sideL[m][k];
        s = fmaf(eg + sd, W1t[k][j], s);
        bb = fmaf(eg * sd, W2t[k][j], bb);
    }
    s = (s > 0.0f) ? s : 0.01f * s;
    bb = (bb > 0.0f) ? bb : 0.01f * bb;
    float v = s + bb;
    if (ego_next)   ego_next[(size_t)n * DOUT + j] = v;
    if (ego_next_h) ego_next_h[(size_t)n * DOUT + j] = f32_to_bf16(v);

    float sq = v * v;
#pragma unroll
    for (int off = DOUT / 2; off > 0; off >>= 1)
        sq += __shfl_xor(sq, off, DOUT);
    float norm = sqrtf(sq);
    norm = (norm > 1e-12f) ? norm : 1e-12f;
    out[(size_t)n * OUTD + out_off + j] = v / norm;
}

// ---------------------------------------------------------------------------
extern "C" void kernel_launch(void* const* d_in, const int* in_sizes, int n_in,
                              void* d_out, int out_size, void* d_ws, size_t ws_size,
                              hipStream_t stream) {
    const float* aux_info  = (const float*)d_in[0];
    const float* entity    = (const float*)d_in[1];
    const float* aux_W     = (const float*)d_in[2];
    const float* aux_b     = (const float*)d_in[3];
    const float* edge_vals = (const float*)d_in[4];
    const int*   edge_rows = (const int*)d_in[5];
    const int*   edge_cols = (const int*)d_in[6];
    const float* W1_0 = (const float*)d_in[7];
    const float* b1_0 = (const float*)d_in[8];
    const float* W2_0 = (const float*)d_in[9];
    const float* b2_0 = (const float*)d_in[10];
    const float* W1_1 = (const float*)d_in[11];
    const float* b1_1 = (const float*)d_in[12];
    const float* W2_1 = (const float*)d_in[13];
    const float* b2_1 = (const float*)d_in[14];
    float* out = (float*)d_out;

    // workspace layout (4-byte words). Aliases:
    //   edges_b (stage-1, dead after csr_sort)  <->  side0 (written by gather64)
    //   ego0h (dead after gather64)             <->  ego1h (written by layer0)
    float* region0 = (float*)d_ws;
    int2*  edges_b = (int2*)region0;                       // 6.4M words
    float* side0   = region0;                              // alias
    float* ego0    = region0 + (size_t)NE * 2;             // 6.4M words
    unsigned short* ego0h = (unsigned short*)(ego0 + (size_t)NN * 64); // 3.2M words
    unsigned short* ego1h = ego0h;                         // alias (1.6M words)
    unsigned int* edges = (unsigned int*)((float*)ego0h + (size_t)NN * 32); // 3.2M words
    float* ego1  = (float*)(edges + NE);                   // 3.2M words
    float* side1 = ego1 + (size_t)NN * 32;                 // 3.2M words
    int* row_ptr     = (int*)(side1 + (size_t)NN * 32);
    int* bucket_base = row_ptr + NN + 1;
    int* gcount      = bucket_base + NBUCK + 1;            // reused as cursor

    // --- CSR build (graph shared by both layers) ---
    hipMemsetAsync(gcount, 0, (size_t)NBUCK * sizeof(int), stream);
    bhist_kernel<<<FILL_B, 256, 0, stream>>>(edge_rows, gcount);
    bscan_kernel<<<1, 1024, 0, stream>>>(gcount, bucket_base, gcount);
    bucket_fill_kernel<<<FILL_B, 256, 0, stream>>>(
        edge_rows, edge_cols, edge_vals, gcount, edges_b);
    csr_sort_kernel<<<NBUCK, 256, 0, stream>>>(edges_b, bucket_base, edges, row_ptr);

    // --- 1) holographic fusion -> ego0 (+bf16), out[:,0:64] ---
    {
        int total = NN * 64;
        fuse_ego_kernel<<<(total + 255) / 256, 256, 0, stream>>>(
            aux_info, entity, aux_W, aux_b, ego0, ego0h, out);
    }
    // --- 2) layer 0 segment-sum (pull, bf16) ---
    gather_kernel<64><<<(NN + 7) / 8, 256, 0, stream>>>(
        (const ushort2*)ego0h, edges, row_ptr, side0);
    // --- 3) layer 0 transform -> ego1 (+bf16), out[:,64:96] ---
    layer_kernel<64, 32, 8><<<(NN + 7) / 8, 256, 0, stream>>>(
        ego0, side0, W1_0, b1_0, W2_0, b2_0, ego1, ego1h, out, 64);
    // --- 4) layer 1 segment-sum (pull, bf16) ---
    gather_kernel<32><<<(NN + 15) / 16, 256, 0, stream>>>(
        (const ushort2*)ego1h, edges, row_ptr, side1);
    // --- 5) layer 1 transform -> out[:,96:112] ---
    layer_kernel<32, 16, 16><<<(NN + 15) / 16, 256, 0, stream>>>(
        ego1, side1, W1_1, b1_1, W2_1, b2_1, nullptr, nullptr, out, 96);
}

// Round 7
// 436.006 us; speedup vs baseline: 5.7621x; 1.0458x over previous
//
#include <hip/hip_runtime.h>
#include <math.h>

#define NN 100000
#define NE 3200000
#define OUTD 112
#define BROWS 128                 // rows per bucket
#define NBUCK 782                 // ceil(NN / BROWS)
#define FILL_CH 4096              // edges per block in hist/fill
#define FILL_B ((NE + FILL_CH - 1) / FILL_CH)   // 782
#define BLD_T 512                 // threads for CSR-build kernels (8 waves)

// round-to-nearest-even fp32 -> bf16 (as raw 16 bits)
__device__ inline unsigned short f32_to_bf16(float f) {
    unsigned u = __float_as_uint(f);
    u += 0x7FFFu + ((u >> 16) & 1u);
    return (unsigned short)(u >> 16);
}
__device__ inline float bf16_bits_to_f32(unsigned b) {
    return __uint_as_float(b << 16);
}

// ---------------------------------------------------------------------------
// Kernel 1: ego = entity_embed * (1 + tanh(aux_info @ aux_W.T + aux_b))
// writes out[:,0:64] (fp32 ego, read back by layer0) + bf16 ego0h (gather).
// ---------------------------------------------------------------------------
__global__ void fuse_ego_kernel(const float* __restrict__ aux_info,
                                const float* __restrict__ entity,
                                const float* __restrict__ aux_W,
                                const float* __restrict__ aux_b,
                                unsigned short* __restrict__ ego0h,
                                float* __restrict__ out) {
    int idx = blockIdx.x * blockDim.x + threadIdx.x;
    if (idx >= NN * 64) return;
    int n = idx >> 6;
    int j = idx & 63;
    float a0 = aux_info[n * 3 + 0];
    float a1 = aux_info[n * 3 + 1];
    float a2 = aux_info[n * 3 + 2];
    float w0 = aux_W[j * 3 + 0];
    float w1 = aux_W[j * 3 + 1];
    float w2 = aux_W[j * 3 + 2];
    float t = tanhf(fmaf(a0, w0, fmaf(a1, w1, fmaf(a2, w2, aux_b[j]))));
    float e = entity[idx] * (1.0f + t);
    ego0h[idx] = f32_to_bf16(e);
    out[(size_t)n * OUTD + j] = e;
}

// ---------------------------------------------------------------------------
// CSR build, stage 1: bucket (128-row granularity) counting sort.
// Stage-1 record: int2 { col | (row%BROWS)<<17 , val-as-fp32-bits }.
// All build kernels use 512 threads: grid is ~3 blocks/CU, so 8 waves/block
// gives 24/32 waves/CU (vs 12 at 256 threads) — these are latency-bound.
// ---------------------------------------------------------------------------
__global__ void bhist_kernel(const int* __restrict__ rows, int* __restrict__ gcount) {
    __shared__ int h[NBUCK];
    for (int i = threadIdx.x; i < NBUCK; i += BLD_T) h[i] = 0;
    __syncthreads();
    int base = blockIdx.x * FILL_CH;
    int nE = NE - base; if (nE > FILL_CH) nE = FILL_CH;
    for (int i = threadIdx.x; i < nE; i += BLD_T)
        atomicAdd(&h[rows[base + i] >> 7], 1);
    __syncthreads();
    for (int i = threadIdx.x; i < NBUCK; i += BLD_T)
        if (h[i]) atomicAdd(&gcount[i], h[i]);
}

__global__ void bscan_kernel(const int* __restrict__ gcount,
                             int* __restrict__ bucket_base,
                             int* __restrict__ gcursor) {
    __shared__ int sh[1024];
    int t = threadIdx.x;
    int v = (t < NBUCK) ? gcount[t] : 0;
    sh[t] = v;
    __syncthreads();
    for (int off = 1; off < 1024; off <<= 1) {
        int u = (t >= off) ? sh[t - off] : 0;
        __syncthreads();
        sh[t] += u;
        __syncthreads();
    }
    if (t < NBUCK) {
        int excl = sh[t] - v;
        bucket_base[t] = excl;
        gcursor[t] = excl;
    }
    if (t == 1023) bucket_base[NBUCK] = sh[1023];
}

__global__ void bucket_fill_kernel(const int* __restrict__ rows,
                                   const int* __restrict__ cols,
                                   const float* __restrict__ vals,
                                   int* __restrict__ gcursor,
                                   int2* __restrict__ edges_b) {
    __shared__ int rowsL[FILL_CH];        // 16 KB
    __shared__ int hcnt[NBUCK];
    __shared__ int curs[NBUCK];
    int base = blockIdx.x * FILL_CH;
    int nE = NE - base; if (nE > FILL_CH) nE = FILL_CH;
    for (int i = threadIdx.x; i < NBUCK; i += BLD_T) hcnt[i] = 0;
    __syncthreads();
    for (int i = threadIdx.x; i < nE; i += BLD_T) {
        int r = rows[base + i];
        rowsL[i] = r;
        atomicAdd(&hcnt[r >> 7], 1);
    }
    __syncthreads();
    for (int b = threadIdx.x; b < NBUCK; b += BLD_T) {
        int c = hcnt[b];
        curs[b] = c ? atomicAdd(&gcursor[b], c) : 0;
    }
    __syncthreads();
    for (int i = threadIdx.x; i < nE; i += BLD_T) {
        int r = rowsL[i];
        int b = r >> 7;
        int p = atomicAdd(&curs[b], 1);
        edges_b[p] = make_int2(cols[base + i] | ((r & (BROWS - 1)) << 17),
                               __float_as_int(vals[base + i]));
    }
}

// ---------------------------------------------------------------------------
// CSR build, stage 2: within-bucket counting sort -> row-sorted PACKED edges
// (uint32 = col | bf15(val)<<17) + row_ptr. One block per bucket.
// ---------------------------------------------------------------------------
__global__ void csr_sort_kernel(const int2* __restrict__ edges_b,
                                const int* __restrict__ bucket_base,
                                unsigned int* __restrict__ edges,
                                int* __restrict__ row_ptr) {
    __shared__ int cnt[BROWS];
    __shared__ int scn[BROWS];
    __shared__ int curs[BROWS];
    int b = blockIdx.x;
    int beg = bucket_base[b], end = bucket_base[b + 1];
    if (threadIdx.x < BROWS) cnt[threadIdx.x] = 0;
    __syncthreads();
    for (int i = beg + threadIdx.x; i < end; i += BLD_T)
        atomicAdd(&cnt[(edges_b[i].x >> 17) & (BROWS - 1)], 1);
    __syncthreads();
    if (threadIdx.x < BROWS) scn[threadIdx.x] = cnt[threadIdx.x];
    __syncthreads();
    for (int off = 1; off < BROWS; off <<= 1) {
        int v = 0;
        if (threadIdx.x < BROWS && threadIdx.x >= off) v = scn[threadIdx.x - off];
        __syncthreads();
        if (threadIdx.x < BROWS && threadIdx.x >= off) scn[threadIdx.x] += v;
        __syncthreads();
    }
    if (threadIdx.x < BROWS) {
        int excl = scn[threadIdx.x] - cnt[threadIdx.x];
        int n = b * BROWS + threadIdx.x;
        if (n <= NN) row_ptr[n] = beg + excl;   // n==NN covered by last bucket
        curs[threadIdx.x] = beg + excl;
    }
    __syncthreads();
    for (int i = beg + threadIdx.x; i < end; i += BLD_T) {
        int2 e = edges_b[i];
        int rl = (e.x >> 17) & (BROWS - 1);
        int p = atomicAdd(&curs[rl], 1);
        unsigned int vb = f32_to_bf16(__int_as_float(e.y)) & 0x7FFFu;  // val>=0
        edges[p] = (unsigned int)(e.x & 0x1FFFF) | (vb << 17);
    }
}

// ---------------------------------------------------------------------------
// Pull-based segment sum, bf16 inputs, fp32 accumulate.
// L = D/2 lanes per node; each lane owns a feature PAIR (ushort2 load).
// Unroll 8 keeps 8 independent gather loads in flight per lane.
// ---------------------------------------------------------------------------
template <int D>
__global__ void gather_kernel(const ushort2* __restrict__ egoh,
                              const unsigned int* __restrict__ edges,
                              const int* __restrict__ row_ptr,
                              float* __restrict__ side) {
    constexpr int L = D / 2;
    int n = blockIdx.x * (256 / L) + threadIdx.x / L;
    int j = threadIdx.x % L;
    if (n >= NN) return;
    int beg = row_ptr[n];
    int end = row_ptr[n + 1];
    float a0 = 0.0f, a1 = 0.0f;
    int i = beg;
    for (; i + 8 <= end; i += 8) {
        unsigned int e[8];
        ushort2 gv[8];
#pragma unroll
        for (int k = 0; k < 8; ++k) e[k] = edges[i + k];
#pragma unroll
        for (int k = 0; k < 8; ++k) gv[k] = egoh[(size_t)(e[k] & 0x1FFFFu) * L + j];
#pragma unroll
        for (int k = 0; k < 8; ++k) {
            float v = bf16_bits_to_f32(e[k] >> 17);   // sign=0
            a0 = fmaf(v, bf16_bits_to_f32(gv[k].x), a0);
            a1 = fmaf(v, bf16_bits_to_f32(gv[k].y), a1);
        }
    }
    for (; i < end; ++i) {
        unsigned int e = edges[i];
        ushort2 g = egoh[(size_t)(e & 0x1FFFFu) * L + j];
        float v = bf16_bits_to_f32(e >> 17);
        a0 = fmaf(v, bf16_bits_to_f32(g.x), a0);
        a1 = fmaf(v, bf16_bits_to_f32(g.y), a1);
    }
    side[(size_t)n * D + 2 * j]     = a0;
    side[(size_t)n * D + 2 * j + 1] = a1;
}

// ---------------------------------------------------------------------------
// Bi-interaction layer + l2norm epilogue. ego read with a stride so layer0
// can read fp32 ego directly from out[:,0:64] (256 B/node contiguous).
// ---------------------------------------------------------------------------
template <int DIN, int DOUT, int NB>
__global__ void layer_kernel(const float* __restrict__ ego, int ego_stride,
                             const float* __restrict__ side,
                             const float* __restrict__ W1,
                             const float* __restrict__ b1,
                             const float* __restrict__ W2,
                             const float* __restrict__ b2,
                             float* __restrict__ ego_next,            // nullable
                             unsigned short* __restrict__ ego_next_h, // nullable
                             float* __restrict__ out,
                             int out_off) {
    __shared__ float W1t[DIN][DOUT + 1];
    __shared__ float W2t[DIN][DOUT + 1];
    __shared__ float egoL[NB][DIN];
    __shared__ float sideL[NB][DIN];

    for (int i = threadIdx.x; i < DIN * DOUT; i += blockDim.x) {
        int j = i / DIN;
        int k = i - j * DIN;
        W1t[k][j] = W1[i];
        W2t[k][j] = W2[i];
    }
    int node0 = blockIdx.x * NB;
    for (int i = threadIdx.x; i < NB * DIN; i += blockDim.x) {
        int m = i / DIN;
        int k = i - m * DIN;
        int n = node0 + m;
        if (n < NN) {
            egoL[m][k] = ego[(size_t)n * ego_stride + k];
            sideL[m][k] = side[(size_t)n * DIN + k];
        }
    }
    __syncthreads();

    int m = threadIdx.x / DOUT;
    int j = threadIdx.x % DOUT;
    int n = node0 + m;
    if (n >= NN) return;

    float s = b1[j];
    float bb = b2[j];
#pragma unroll
    for (int k = 0; k < DIN; ++k) {
        float eg = egoL[m][k];
        float sd = sideL[m][k];
        s = fmaf(eg + sd, W1t[k][j], s);
        bb = fmaf(eg * sd, W2t[k][j], bb);
    }
    s = (s > 0.0f) ? s : 0.01f * s;
    bb = (bb > 0.0f) ? bb : 0.01f * bb;
    float v = s + bb;
    if (ego_next)   ego_next[(size_t)n * DOUT + j] = v;
    if (ego_next_h) ego_next_h[(size_t)n * DOUT + j] = f32_to_bf16(v);

    float sq = v * v;
#pragma unroll
    for (int off = DOUT / 2; off > 0; off >>= 1)
        sq += __shfl_xor(sq, off, DOUT);
    float norm = sqrtf(sq);
    norm = (norm > 1e-12f) ? norm : 1e-12f;
    out[(size_t)n * OUTD + out_off + j] = v / norm;
}

// ---------------------------------------------------------------------------
extern "C" void kernel_launch(void* const* d_in, const int* in_sizes, int n_in,
                              void* d_out, int out_size, void* d_ws, size_t ws_size,
                              hipStream_t stream) {
    const float* aux_info  = (const float*)d_in[0];
    const float* entity    = (const float*)d_in[1];
    const float* aux_W     = (const float*)d_in[2];
    const float* aux_b     = (const float*)d_in[3];
    const float* edge_vals = (const float*)d_in[4];
    const int*   edge_rows = (const int*)d_in[5];
    const int*   edge_cols = (const int*)d_in[6];
    const float* W1_0 = (const float*)d_in[7];
    const float* b1_0 = (const float*)d_in[8];
    const float* W2_0 = (const float*)d_in[9];
    const float* b2_0 = (const float*)d_in[10];
    const float* W1_1 = (const float*)d_in[11];
    const float* b1_1 = (const float*)d_in[12];
    const float* W2_1 = (const float*)d_in[13];
    const float* b2_1 = (const float*)d_in[14];
    float* out = (float*)d_out;

    // workspace layout (4-byte words). Aliases:
    //   edges_b (stage-1, dead after csr_sort)  <->  side0 (written by gather64)
    //   ego0h (dead after gather64)             <->  ego1h (written by layer0)
    float* region0 = (float*)d_ws;
    int2*  edges_b = (int2*)region0;                       // 6.4M words
    float* side0   = region0;                              // alias
    unsigned short* ego0h = (unsigned short*)(region0 + (size_t)NE * 2); // 3.2M words
    unsigned short* ego1h = ego0h;                         // alias (1.6M words)
    unsigned int* edges = (unsigned int*)((float*)ego0h + (size_t)NN * 32); // 3.2M words
    float* ego1  = (float*)(edges + NE);                   // 3.2M words
    float* side1 = ego1 + (size_t)NN * 32;                 // 3.2M words
    int* row_ptr     = (int*)(side1 + (size_t)NN * 32);
    int* bucket_base = row_ptr + NN + 1;
    int* gcount      = bucket_base + NBUCK + 1;            // reused as cursor

    // --- CSR build (graph shared by both layers) ---
    hipMemsetAsync(gcount, 0, (size_t)NBUCK * sizeof(int), stream);
    bhist_kernel<<<FILL_B, BLD_T, 0, stream>>>(edge_rows, gcount);
    bscan_kernel<<<1, 1024, 0, stream>>>(gcount, bucket_base, gcount);
    bucket_fill_kernel<<<FILL_B, BLD_T, 0, stream>>>(
        edge_rows, edge_cols, edge_vals, gcount, edges_b);
    csr_sort_kernel<<<NBUCK, BLD_T, 0, stream>>>(edges_b, bucket_base, edges, row_ptr);

    // --- 1) holographic fusion -> out[:,0:64] (fp32 ego) + bf16 ego0h ---
    {
        int total = NN * 64;
        fuse_ego_kernel<<<(total + 255) / 256, 256, 0, stream>>>(
            aux_info, entity, aux_W, aux_b, ego0h, out);
    }
    // --- 2) layer 0 segment-sum (pull, bf16) ---
    gather_kernel<64><<<(NN + 7) / 8, 256, 0, stream>>>(
        (const ushort2*)ego0h, edges, row_ptr, side0);
    // --- 3) layer 0 transform (ego read from out[:,0:64]) -> ego1 (+bf16) ---
    layer_kernel<64, 32, 8><<<(NN + 7) / 8, 256, 0, stream>>>(
        out, OUTD, side0, W1_0, b1_0, W2_0, b2_0, ego1, ego1h, out, 64);
    // --- 4) layer 1 segment-sum (pull, bf16) ---
    gather_kernel<32><<<(NN + 15) / 16, 256, 0, stream>>>(
        (const ushort2*)ego1h, edges, row_ptr, side1);
    // --- 5) layer 1 transform -> out[:,96:112] ---
    layer_kernel<32, 16, 16><<<(NN + 15) / 16, 256, 0, stream>>>(
        ego1, 32, side1, W1_1, b1_1, W2_1, b2_1, nullptr, nullptr, out, 96);
}

// Round 8
// 414.061 us; speedup vs baseline: 6.0675x; 1.0530x over previous
//
#include <hip/hip_runtime.h>
#include <math.h>

#define NN 100000
#define NE 3200000
#define OUTD 112
#define BROWS 512                 // rows per bucket (9-bit local row)
#define NBUCK 196                 // ceil(NN / BROWS)
#define FILL_CH 8192              // edges per block in hist/fill
#define FILL_B ((NE + FILL_CH - 1) / FILL_CH)   // 391
#define BLD1_T 1024               // threads for bhist/bucket_fill (16 waves)
#define SORT_T 512                // threads for csr_sort

// round-to-nearest-even fp32 -> bf16 (as raw 16 bits)
__device__ inline unsigned short f32_to_bf16(float f) {
    unsigned u = __float_as_uint(f);
    u += 0x7FFFu + ((u >> 16) & 1u);
    return (unsigned short)(u >> 16);
}
__device__ inline float bf16_bits_to_f32(unsigned b) {
    return __uint_as_float(b << 16);
}

// ---------------------------------------------------------------------------
// Kernel 1: ego = entity_embed * (1 + tanh(aux_info @ aux_W.T + aux_b))
// writes out[:,0:64] (fp32 ego, read back by layer0) + bf16 ego0h (gather).
// ---------------------------------------------------------------------------
__global__ void fuse_ego_kernel(const float* __restrict__ aux_info,
                                const float* __restrict__ entity,
                                const float* __restrict__ aux_W,
                                const float* __restrict__ aux_b,
                                unsigned short* __restrict__ ego0h,
                                float* __restrict__ out) {
    int idx = blockIdx.x * blockDim.x + threadIdx.x;
    if (idx >= NN * 64) return;
    int n = idx >> 6;
    int j = idx & 63;
    float a0 = aux_info[n * 3 + 0];
    float a1 = aux_info[n * 3 + 1];
    float a2 = aux_info[n * 3 + 2];
    float w0 = aux_W[j * 3 + 0];
    float w1 = aux_W[j * 3 + 1];
    float w2 = aux_W[j * 3 + 2];
    float t = tanhf(fmaf(a0, w0, fmaf(a1, w1, fmaf(a2, w2, aux_b[j]))));
    float e = entity[idx] * (1.0f + t);
    ego0h[idx] = f32_to_bf16(e);
    out[(size_t)n * OUTD + j] = e;
}

// ---------------------------------------------------------------------------
// CSR build, stage 1: bucket (512-row granularity) counting sort.
// Stage-1 record: int2 { col | (row%BROWS)<<17 , val-as-fp32-bits }.
// Big buckets + big chunks: per (block,bucket) write burst ~42 edges = 334 B
// (>2 cache lines) — fixes the 3x partial-line write amplification seen at
// BROWS=128/FILL_CH=4096 (WRITE_SIZE 79 MB for 25.6 MB payload).
// ---------------------------------------------------------------------------
__global__ void bhist_kernel(const int* __restrict__ rows, int* __restrict__ gcount) {
    __shared__ int h[NBUCK];
    for (int i = threadIdx.x; i < NBUCK; i += BLD1_T) h[i] = 0;
    __syncthreads();
    int base = blockIdx.x * FILL_CH;
    int nE = NE - base; if (nE > FILL_CH) nE = FILL_CH;
    for (int i = threadIdx.x; i < nE; i += BLD1_T)
        atomicAdd(&h[rows[base + i] >> 9], 1);
    __syncthreads();
    for (int i = threadIdx.x; i < NBUCK; i += BLD1_T)
        if (h[i]) atomicAdd(&gcount[i], h[i]);
}

__global__ void bscan_kernel(const int* __restrict__ gcount,
                             int* __restrict__ bucket_base,
                             int* __restrict__ gcursor) {
    __shared__ int sh[256];
    int t = threadIdx.x;
    int v = (t < NBUCK) ? gcount[t] : 0;
    sh[t] = v;
    __syncthreads();
    for (int off = 1; off < 256; off <<= 1) {
        int u = (t >= off) ? sh[t - off] : 0;
        __syncthreads();
        sh[t] += u;
        __syncthreads();
    }
    if (t < NBUCK) {
        int excl = sh[t] - v;
        bucket_base[t] = excl;
        gcursor[t] = excl;
    }
    if (t == 255) bucket_base[NBUCK] = sh[255];
}

__global__ void bucket_fill_kernel(const int* __restrict__ rows,
                                   const int* __restrict__ cols,
                                   const float* __restrict__ vals,
                                   int* __restrict__ gcursor,
                                   int2* __restrict__ edges_b) {
    __shared__ int rowsL[FILL_CH];        // 32 KB
    __shared__ int hcnt[NBUCK];
    __shared__ int curs[NBUCK];
    int base = blockIdx.x * FILL_CH;
    int nE = NE - base; if (nE > FILL_CH) nE = FILL_CH;
    for (int i = threadIdx.x; i < NBUCK; i += BLD1_T) hcnt[i] = 0;
    __syncthreads();
    for (int i = threadIdx.x; i < nE; i += BLD1_T) {
        int r = rows[base + i];
        rowsL[i] = r;
        atomicAdd(&hcnt[r >> 9], 1);
    }
    __syncthreads();
    for (int b = threadIdx.x; b < NBUCK; b += BLD1_T) {
        int c = hcnt[b];
        curs[b] = c ? atomicAdd(&gcursor[b], c) : 0;
    }
    __syncthreads();
    for (int i = threadIdx.x; i < nE; i += BLD1_T) {
        int r = rowsL[i];
        int b = r >> 9;
        int p = atomicAdd(&curs[b], 1);
        edges_b[p] = make_int2(cols[base + i] | ((r & (BROWS - 1)) << 17),
                               __float_as_int(vals[base + i]));
    }
}

// ---------------------------------------------------------------------------
// CSR build, stage 2: within-bucket counting sort -> row-sorted PACKED edges
// (uint32 = col | bf15(val)<<17) + row_ptr. One block per 512-row bucket;
// per-row write burst = ~32 edges x 4 B = one full line.
// ---------------------------------------------------------------------------
__global__ void csr_sort_kernel(const int2* __restrict__ edges_b,
                                const int* __restrict__ bucket_base,
                                unsigned int* __restrict__ edges,
                                int* __restrict__ row_ptr) {
    __shared__ int cnt[BROWS];
    __shared__ int scn[BROWS];
    __shared__ int curs[BROWS];
    int b = blockIdx.x;
    int beg = bucket_base[b], end = bucket_base[b + 1];
    int t = threadIdx.x;
    cnt[t] = 0;
    __syncthreads();
    for (int i = beg + t; i < end; i += SORT_T)
        atomicAdd(&cnt[(edges_b[i].x >> 17) & (BROWS - 1)], 1);
    __syncthreads();
    scn[t] = cnt[t];
    __syncthreads();
    for (int off = 1; off < BROWS; off <<= 1) {
        int v = (t >= off) ? scn[t - off] : 0;
        __syncthreads();
        scn[t] += v;
        __syncthreads();
    }
    {
        int excl = scn[t] - cnt[t];
        int n = b * BROWS + t;
        if (n <= NN) row_ptr[n] = beg + excl;   // n==NN covered by last bucket
        curs[t] = beg + excl;
    }
    __syncthreads();
    for (int i = beg + t; i < end; i += SORT_T) {
        int2 e = edges_b[i];
        int rl = (e.x >> 17) & (BROWS - 1);
        int p = atomicAdd(&curs[rl], 1);
        unsigned int vb = f32_to_bf16(__int_as_float(e.y)) & 0x7FFFu;  // val>=0
        edges[p] = (unsigned int)(e.x & 0x1FFFF) | (vb << 17);
    }
}

// ---------------------------------------------------------------------------
// Pull-based segment sum, bf16 inputs, fp32 accumulate.
// L = D/2 lanes per node; each lane owns a feature PAIR (ushort2 load).
// Unroll 8 keeps 8 independent gather loads in flight per lane.
// ---------------------------------------------------------------------------
template <int D>
__global__ void gather_kernel(const ushort2* __restrict__ egoh,
                              const unsigned int* __restrict__ edges,
                              const int* __restrict__ row_ptr,
                              float* __restrict__ side) {
    constexpr int L = D / 2;
    int n = blockIdx.x * (256 / L) + threadIdx.x / L;
    int j = threadIdx.x % L;
    if (n >= NN) return;
    int beg = row_ptr[n];
    int end = row_ptr[n + 1];
    float a0 = 0.0f, a1 = 0.0f;
    int i = beg;
    for (; i + 8 <= end; i += 8) {
        unsigned int e[8];
        ushort2 gv[8];
#pragma unroll
        for (int k = 0; k < 8; ++k) e[k] = edges[i + k];
#pragma unroll
        for (int k = 0; k < 8; ++k) gv[k] = egoh[(size_t)(e[k] & 0x1FFFFu) * L + j];
#pragma unroll
        for (int k = 0; k < 8; ++k) {
            float v = bf16_bits_to_f32(e[k] >> 17);   // sign=0
            a0 = fmaf(v, bf16_bits_to_f32(gv[k].x), a0);
            a1 = fmaf(v, bf16_bits_to_f32(gv[k].y), a1);
        }
    }
    for (; i < end; ++i) {
        unsigned int e = edges[i];
        ushort2 g = egoh[(size_t)(e & 0x1FFFFu) * L + j];
        float v = bf16_bits_to_f32(e >> 17);
        a0 = fmaf(v, bf16_bits_to_f32(g.x), a0);
        a1 = fmaf(v, bf16_bits_to_f32(g.y), a1);
    }
    side[(size_t)n * D + 2 * j]     = a0;
    side[(size_t)n * D + 2 * j + 1] = a1;
}

// ---------------------------------------------------------------------------
// Bi-interaction layer + l2norm epilogue. ego read with a stride so layer0
// can read fp32 ego directly from out[:,0:64] (256 B/node contiguous).
// ---------------------------------------------------------------------------
template <int DIN, int DOUT, int NB>
__global__ void layer_kernel(const float* __restrict__ ego, int ego_stride,
                             const float* __restrict__ side,
                             const float* __restrict__ W1,
                             const float* __restrict__ b1,
                             const float* __restrict__ W2,
                             const float* __restrict__ b2,
                             float* __restrict__ ego_next,            // nullable
                             unsigned short* __restrict__ ego_next_h, // nullable
                             float* __restrict__ out,
                             int out_off) {
    __shared__ float W1t[DIN][DOUT + 1];
    __shared__ float W2t[DIN][DOUT + 1];
    __shared__ float egoL[NB][DIN];
    __shared__ float sideL[NB][DIN];

    for (int i = threadIdx.x; i < DIN * DOUT; i += blockDim.x) {
        int j = i / DIN;
        int k = i - j * DIN;
        W1t[k][j] = W1[i];
        W2t[k][j] = W2[i];
    }
    int node0 = blockIdx.x * NB;
    for (int i = threadIdx.x; i < NB * DIN; i += blockDim.x) {
        int m = i / DIN;
        int k = i - m * DIN;
        int n = node0 + m;
        if (n < NN) {
            egoL[m][k] = ego[(size_t)n * ego_stride + k];
            sideL[m][k] = side[(size_t)n * DIN + k];
        }
    }
    __syncthreads();

    int m = threadIdx.x / DOUT;
    int j = threadIdx.x % DOUT;
    int n = node0 + m;
    if (n >= NN) return;

    float s = b1[j];
    float bb = b2[j];
#pragma unroll
    for (int k = 0; k < DIN; ++k) {
        float eg = egoL[m][k];
        float sd = sideL[m][k];
        s = fmaf(eg + sd, W1t[k][j], s);
        bb = fmaf(eg * sd, W2t[k][j], bb);
    }
    s = (s > 0.0f) ? s : 0.01f * s;
    bb = (bb > 0.0f) ? bb : 0.01f * bb;
    float v = s + bb;
    if (ego_next)   ego_next[(size_t)n * DOUT + j] = v;
    if (ego_next_h) ego_next_h[(size_t)n * DOUT + j] = f32_to_bf16(v);

    float sq = v * v;
#pragma unroll
    for (int off = DOUT / 2; off > 0; off >>= 1)
        sq += __shfl_xor(sq, off, DOUT);
    float norm = sqrtf(sq);
    norm = (norm > 1e-12f) ? norm : 1e-12f;
    out[(size_t)n * OUTD + out_off + j] = v / norm;
}

// ---------------------------------------------------------------------------
extern "C" void kernel_launch(void* const* d_in, const int* in_sizes, int n_in,
                              void* d_out, int out_size, void* d_ws, size_t ws_size,
                              hipStream_t stream) {
    const float* aux_info  = (const float*)d_in[0];
    const float* entity    = (const float*)d_in[1];
    const float* aux_W     = (const float*)d_in[2];
    const float* aux_b     = (const float*)d_in[3];
    const float* edge_vals = (const float*)d_in[4];
    const int*   edge_rows = (const int*)d_in[5];
    const int*   edge_cols = (const int*)d_in[6];
    const float* W1_0 = (const float*)d_in[7];
    const float* b1_0 = (const float*)d_in[8];
    const float* W2_0 = (const float*)d_in[9];
    const float* b2_0 = (const float*)d_in[10];
    const float* W1_1 = (const float*)d_in[11];
    const float* b1_1 = (const float*)d_in[12];
    const float* W2_1 = (const float*)d_in[13];
    const float* b2_1 = (const float*)d_in[14];
    float* out = (float*)d_out;

    // workspace layout (4-byte words). Aliases:
    //   edges_b (stage-1, dead after csr_sort)  <->  side0 (written by gather64)
    //   ego0h (dead after gather64)             <->  ego1h (written by layer0)
    float* region0 = (float*)d_ws;
    int2*  edges_b = (int2*)region0;                       // 6.4M words
    float* side0   = region0;                              // alias
    unsigned short* ego0h = (unsigned short*)(region0 + (size_t)NE * 2); // 3.2M words
    unsigned short* ego1h = ego0h;                         // alias (1.6M words)
    unsigned int* edges = (unsigned int*)((float*)ego0h + (size_t)NN * 32); // 3.2M words
    float* ego1  = (float*)(edges + NE);                   // 3.2M words
    float* side1 = ego1 + (size_t)NN * 32;                 // 3.2M words
    int* row_ptr     = (int*)(side1 + (size_t)NN * 32);
    int* bucket_base = row_ptr + NN + 1;
    int* gcount      = bucket_base + NBUCK + 1;            // reused as cursor

    // --- CSR build (graph shared by both layers) ---
    hipMemsetAsync(gcount, 0, (size_t)NBUCK * sizeof(int), stream);
    bhist_kernel<<<FILL_B, BLD1_T, 0, stream>>>(edge_rows, gcount);
    bscan_kernel<<<1, 256, 0, stream>>>(gcount, bucket_base, gcount);
    bucket_fill_kernel<<<FILL_B, BLD1_T, 0, stream>>>(
        edge_rows, edge_cols, edge_vals, gcount, edges_b);
    csr_sort_kernel<<<NBUCK, SORT_T, 0, stream>>>(edges_b, bucket_base, edges, row_ptr);

    // --- 1) holographic fusion -> out[:,0:64] (fp32 ego) + bf16 ego0h ---
    {
        int total = NN * 64;
        fuse_ego_kernel<<<(total + 255) / 256, 256, 0, stream>>>(
            aux_info, entity, aux_W, aux_b, ego0h, out);
    }
    // --- 2) layer 0 segment-sum (pull, bf16) ---
    gather_kernel<64><<<(NN + 7) / 8, 256, 0, stream>>>(
        (const ushort2*)ego0h, edges, row_ptr, side0);
    // --- 3) layer 0 transform (ego read from out[:,0:64]) -> ego1 (+bf16) ---
    layer_kernel<64, 32, 8><<<(NN + 7) / 8, 256, 0, stream>>>(
        out, OUTD, side0, W1_0, b1_0, W2_0, b2_0, ego1, ego1h, out, 64);
    // --- 4) layer 1 segment-sum (pull, bf16) ---
    gather_kernel<32><<<(NN + 15) / 16, 256, 0, stream>>>(
        (const ushort2*)ego1h, edges, row_ptr, side1);
    // --- 5) layer 1 transform -> out[:,96:112] ---
    layer_kernel<32, 16, 16><<<(NN + 15) / 16, 256, 0, stream>>>(
        ego1, 32, side1, W1_1, b1_1, W2_1, b2_1, nullptr, nullptr, out, 96);
}